// Round 14
// baseline (845.106 us; speedup 1.0000x reference)
//
#include <hip/hip_runtime.h>
#include <hip/hip_cooperative_groups.h>
namespace coop = cooperative_groups;

#define IN_CH 128
#define HID 64
#define TILE 8192     // edges per partition tile
#define B2SHIFT 10
#define B2NODES 1024  // nodes per bucket; pack (dlocal<<17)|src needs N < 2^17

// ---------------- shared gather inner loop: sum_{s in list} g[s][lane] ----------------
__device__ __forceinline__ float gather_row(const int* __restrict__ csr, int start, int deg,
                                            const float* __restrict__ g, int lane) {
  float sum = 0.f;
  for (int c = 0; c < deg; c += 64) {
    int rem = deg - c;
    int cnt = rem < 64 ? rem : 64;
    int idx = 0;
    if (lane < cnt) idx = csr[start + c + lane];
    int j = 0;
    for (; j + 8 <= cnt; j += 8) {
      int s0 = __shfl(idx, j, 64);
      int s1 = __shfl(idx, j + 1, 64);
      int s2 = __shfl(idx, j + 2, 64);
      int s3 = __shfl(idx, j + 3, 64);
      int s4 = __shfl(idx, j + 4, 64);
      int s5 = __shfl(idx, j + 5, 64);
      int s6 = __shfl(idx, j + 6, 64);
      int s7 = __shfl(idx, j + 7, 64);
      float a0 = g[(size_t)s0 * HID + lane];
      float a1 = g[(size_t)s1 * HID + lane];
      float a2 = g[(size_t)s2 * HID + lane];
      float a3 = g[(size_t)s3 * HID + lane];
      float a4 = g[(size_t)s4 * HID + lane];
      float a5 = g[(size_t)s5 * HID + lane];
      float a6 = g[(size_t)s6 * HID + lane];
      float a7 = g[(size_t)s7 * HID + lane];
      sum += a0; sum += a1; sum += a2; sum += a3;
      sum += a4; sum += a5; sum += a6; sum += a7;
    }
    for (; j + 4 <= cnt; j += 4) {
      int s0 = __shfl(idx, j, 64);
      int s1 = __shfl(idx, j + 1, 64);
      int s2 = __shfl(idx, j + 2, 64);
      int s3 = __shfl(idx, j + 3, 64);
      float a0 = g[(size_t)s0 * HID + lane];
      float a1 = g[(size_t)s1 * HID + lane];
      float a2 = g[(size_t)s2 * HID + lane];
      float a3 = g[(size_t)s3 * HID + lane];
      sum += a0; sum += a1; sum += a2; sum += a3;
    }
    for (; j < cnt; ++j)
      sum += g[(size_t)__shfl(idx, j, 64) * HID + lane];
  }
  return sum;
}

// ============ K1: cooperative build — hist, colscan, bbase+partition, finalize, gemm1 ============
__global__ __launch_bounds__(256) void k_build(const int* __restrict__ src,
    const int* __restrict__ dst, const float* __restrict__ x,
    const float* __restrict__ W1, int* __restrict__ H, int* __restrict__ Orel,
    int* __restrict__ colTot, unsigned* __restrict__ pairBuf,
    int* __restrict__ csr, int* __restrict__ rowptr, int* __restrict__ degInt,
    float* __restrict__ dinv, float* __restrict__ g1,
    int N, int E, int nblk, int gb) {
  coop::grid_group grid = coop::this_grid();
  __shared__ __align__(16) float sh[16384];  // 64 KB union buffer
  const int tid = threadIdx.x;
  const int P = (N + B2NODES - 1) >> B2SHIFT;  // 98

  // ---- phase 1: per-tile coarse histogram (LDS atomics only) ----
  {
    int* cnt = (int*)sh;
    for (int t = blockIdx.x; t < nblk; t += gridDim.x) {
      for (int i = tid; i < P; i += 256) cnt[i] = 0;
      __syncthreads();
      const int b0 = t * TILE;
      const int b1e = min(b0 + TILE, E);
      for (int i = b0 + tid; i < b1e; i += 256)
        atomicAdd(&cnt[dst[i] >> B2SHIFT], 1);
      __syncthreads();
      for (int i = tid; i < P; i += 256) H[t * P + i] = cnt[i];
      __syncthreads();
    }
  }
  grid.sync();
  // ---- phase 2: per-bucket exclusive prefix over tiles ----
  if (blockIdx.x < P) {
    int* s = (int*)sh;
    const int b = blockIdx.x;
    const int iA = tid, iB = tid + 256;
    int origA = (iA < nblk) ? H[iA * P + b] : 0;
    int origB = (iB < nblk) ? H[iB * P + b] : 0;
    s[iA] = origA; s[iB] = origB;
    __syncthreads();
    for (int off = 1; off < 512; off <<= 1) {
      int tA = (iA >= off) ? s[iA - off] : 0;
      int tB = (iB >= off) ? s[iB - off] : 0;
      __syncthreads();
      s[iA] += tA; s[iB] += tB;
      __syncthreads();
    }
    if (iA < nblk) Orel[iA * P + b] = s[iA] - origA;
    if (iB < nblk) Orel[iB * P + b] = s[iB] - origB;
    if (tid == 255) colTot[b] = s[511];
  }
  grid.sync();
  // ---- phase 3: bucket-base prescan (redundant per block, stays in LDS) + partition ----
  {
    int* bb  = (int*)sh;          // [128] exclusive bucket bases; bb[P] = E
    int* off = (int*)sh + 128;    // [1024]
    int* cur = (int*)sh + 1152;   // [1024]
    int myv = 0;
    if (tid < 128) { myv = (tid < P) ? colTot[tid] : 0; bb[tid] = myv; }
    __syncthreads();
    for (int o = 1; o < 128; o <<= 1) {
      int t2 = (tid < 128 && tid >= o) ? bb[tid - o] : 0;
      __syncthreads();
      if (tid < 128) bb[tid] += t2;
      __syncthreads();
    }
    if (tid < 128) bb[tid] -= myv;   // exclusive; bb[P]=E since colTot[>=P]=0
    __syncthreads();
    for (int t = blockIdx.x; t < nblk; t += gridDim.x) {
      for (int i = tid; i < P; i += 256) { off[i] = bb[i] + Orel[t * P + i]; cur[i] = 0; }
      __syncthreads();
      const int b0 = t * TILE;
      const int b1e = min(b0 + TILE, E);
      for (int i = b0 + tid; i < b1e; i += 256) {
        int d = dst[i];
        int b = d >> B2SHIFT;
        int r = atomicAdd(&cur[b], 1);  // LDS cursor: per-CU, low contention
        pairBuf[off[b] + r] = ((unsigned)(d & (B2NODES - 1)) << 17) | (unsigned)src[i];
      }
      __syncthreads();
    }
  }
  grid.sync();
  // ---- phase 4: per-bucket finalize (count, scan, rowptr/deg/dinv, scatter CSR) ----
  // bb[0..P] persists in LDS from phase 3 (blocks stay resident across grid.sync).
  if (blockIdx.x < P) {
    int* bb   = (int*)sh;           // [128] (preserved)
    int* cnt  = (int*)sh + 128;     // [1024]
    int* pfx  = (int*)sh + 1152;    // [1024]
    int* cur  = (int*)sh + 2176;    // [1024]
    int* lsum = (int*)sh + 3200;    // [256]
    const int b = blockIdx.x;
    const int e0 = bb[b], e1 = bb[b + 1];
    for (int i = tid; i < B2NODES; i += 256) { cnt[i] = 0; cur[i] = 0; }
    __syncthreads();
    for (int i = e0 + tid; i < e1; i += 256)
      atomicAdd(&cnt[pairBuf[i] >> 17], 1);
    __syncthreads();
    int v[4], tsum = 0;
    #pragma unroll
    for (int k = 0; k < 4; ++k) { v[k] = cnt[tid * 4 + k]; tsum += v[k]; }
    lsum[tid] = tsum;
    __syncthreads();
    for (int off = 1; off < 256; off <<= 1) {
      int t = (tid >= off) ? lsum[tid - off] : 0;
      __syncthreads();
      lsum[tid] += t;
      __syncthreads();
    }
    int run = lsum[tid] - tsum;
    #pragma unroll
    for (int k = 0; k < 4; ++k) { pfx[tid * 4 + k] = run; run += v[k]; }
    __syncthreads();
    #pragma unroll
    for (int k = 0; k < 4; ++k) {
      int l = tid * 4 + k;
      int node = (b << B2SHIFT) + l;
      if (node < N) {
        rowptr[node] = e0 + pfx[l];
        degInt[node] = cnt[l];
        dinv[node]   = 1.0f / sqrtf((float)cnt[l] + 1.0f);  // +1 self-loop
      }
    }
    __syncthreads();
    for (int i = e0 + tid; i < e1; i += 256) {
      unsigned u = pairBuf[i];
      int dl = u >> 17;
      int r = atomicAdd(&cur[dl], 1);
      csr[e0 + pfx[dl] + r] = (int)(u & 0x1FFFFu);
    }
  }
  grid.sync();
  // ---- phase 5: g1 = (x @ W1) * dinv, grid-stride over 64-node tiles ----
  {
    float* Ws = sh;           // [8192] = 32 KB, [k][ch]
    float* xs = sh + 8192;    // [8192] = 32 KB, swizzled
    for (int i = tid; i < IN_CH * HID; i += 256) Ws[i] = W1[i];  // staged once
    const int w = tid >> 6, lane = tid & 63;
    const int ng = lane >> 4, cg_ = lane & 15;
    for (int t = blockIdx.x; t < gb; t += gridDim.x) {
      __syncthreads();  // protect xs (prev iter readers) and cover Ws on first iter
      const int base = t * 64;
      for (int i = tid; i < 64 * IN_CH; i += 256) {
        int row = i >> 7, col = i & 127;
        int n = base + row; if (n > N - 1) n = N - 1;
        xs[(row << 7) + (col ^ (row & 3))] = x[(size_t)n * IN_CH + col];
      }
      __syncthreads();
      float acc[4][4];
      #pragma unroll
      for (int j = 0; j < 4; ++j)
        #pragma unroll
        for (int c = 0; c < 4; ++c) acc[j][c] = 0.f;
      #pragma unroll 8
      for (int k = 0; k < IN_CH; ++k) {
        float4 wv = *(const float4*)&Ws[(k << 6) + (cg_ << 2)];
        #pragma unroll
        for (int j = 0; j < 4; ++j) {
          int row = w * 16 + j * 4 + ng;          // row & 3 == ng
          float xv = xs[(row << 7) + (k ^ ng)];
          acc[j][0] = fmaf(xv, wv.x, acc[j][0]);
          acc[j][1] = fmaf(xv, wv.y, acc[j][1]);
          acc[j][2] = fmaf(xv, wv.z, acc[j][2]);
          acc[j][3] = fmaf(xv, wv.w, acc[j][3]);
        }
      }
      #pragma unroll
      for (int j = 0; j < 4; ++j) {
        int node = base + w * 16 + j * 4 + ng;
        if (node < N) {
          float di = dinv[node];
          float4 gv;
          gv.x = acc[j][0] * di; gv.y = acc[j][1] * di;
          gv.z = acc[j][2] * di; gv.w = acc[j][3] * di;
          *(float4*)&g1[(size_t)node * HID + (cg_ << 2)] = gv;
        }
      }
    }
  }
}

// ============ K2: fused gather(g1) + layer-2 GEMM -> g2 ============
__global__ __launch_bounds__(256) void k_gg2(const int* __restrict__ rowptr,
    const int* __restrict__ degInt, const int* __restrict__ csr,
    const float* __restrict__ g1, const float* __restrict__ dinv,
    const float* __restrict__ b1, const float* __restrict__ W2,
    float* __restrict__ g2, int N) {
  __shared__ __align__(16) float Ws[HID * HID];  // 16 KB
  __shared__ __align__(16) float vs[64 * HID];   // 16 KB, swizzled
  const int tid = threadIdx.x;
  const int base = blockIdx.x * 64;
  for (int i = tid; i < HID * HID; i += 256) Ws[i] = W2[i];
  const int w = tid >> 6, lane = tid & 63;
  const float b1v = b1[lane];
  // gather phase: wave w fills rows [16w, 16w+16)
  for (int j = 0; j < 16; ++j) {
    int row = (w << 4) + j;
    int n = base + row; if (n > N - 1) n = N - 1;
    float sum = g1[(size_t)n * HID + lane]
              + gather_row(csr, rowptr[n], degInt[n], g1, lane);
    vs[(row << 6) + (lane ^ (row & 3))] = fmaf(sum, dinv[n], b1v);
  }
  __syncthreads();
  // GEMM phase: g2 = (v @ W2) * dinv
  const int ng = lane >> 4, cg_ = lane & 15;
  float acc[4][4];
  #pragma unroll
  for (int j = 0; j < 4; ++j)
    #pragma unroll
    for (int c = 0; c < 4; ++c) acc[j][c] = 0.f;
  #pragma unroll 8
  for (int k = 0; k < HID; ++k) {
    float4 wv = *(const float4*)&Ws[(k << 6) + (cg_ << 2)];
    #pragma unroll
    for (int j = 0; j < 4; ++j) {
      int row = w * 16 + j * 4 + ng;
      float xv = vs[(row << 6) + (k ^ ng)];
      acc[j][0] = fmaf(xv, wv.x, acc[j][0]);
      acc[j][1] = fmaf(xv, wv.y, acc[j][1]);
      acc[j][2] = fmaf(xv, wv.z, acc[j][2]);
      acc[j][3] = fmaf(xv, wv.w, acc[j][3]);
    }
  }
  #pragma unroll
  for (int j = 0; j < 4; ++j) {
    int node = base + w * 16 + j * 4 + ng;
    if (node < N) {
      float di = dinv[node];
      float4 gv;
      gv.x = acc[j][0] * di; gv.y = acc[j][1] * di;
      gv.z = acc[j][2] * di; gv.w = acc[j][3] * di;
      *(float4*)&g2[(size_t)node * HID + (cg_ << 2)] = gv;
    }
  }
}

// ============ K3: fused gather(g2) + MLP head -> out ============
__global__ __launch_bounds__(256) void k_gmlp(const int* __restrict__ rowptr,
    const int* __restrict__ degInt, const int* __restrict__ csr,
    const float* __restrict__ g2, const float* __restrict__ dinv,
    const float* __restrict__ b2,
    const float* __restrict__ lw1, const float* __restrict__ lb1,
    const float* __restrict__ lw2, const float* __restrict__ lb2,
    const float* __restrict__ lw3, const float* __restrict__ lb3,
    float* __restrict__ out, int N) {
  __shared__ __align__(16) float w1s[64 * 64];   // 16 KB
  __shared__ __align__(16) float w2s[64 * 32];   // 8 KB
  __shared__ float w3s[32], lb1s[64], lb2s[32];
  __shared__ __align__(16) float vs[64 * 64];    // 16 KB, swizzled
  __shared__ __align__(16) float t1s[64 * 64];   // 16 KB, swizzled
  const int tid = threadIdx.x;
  const int base = blockIdx.x * 64;
  for (int i = tid; i < 4096; i += 256) w1s[i] = lw1[i];
  for (int i = tid; i < 2048; i += 256) w2s[i] = lw2[i];
  if (tid < 64) lb1s[tid] = lb1[tid];
  if (tid < 32) { w3s[tid] = lw3[tid]; lb2s[tid] = lb2[tid]; }
  const float lb3v = lb3[0];
  const int w = tid >> 6, lane = tid & 63;
  const float b2v = b2[lane];
  // gather phase
  for (int j = 0; j < 16; ++j) {
    int row = (w << 4) + j;
    int n = base + row; if (n > N - 1) n = N - 1;
    float sum = g2[(size_t)n * HID + lane]
              + gather_row(csr, rowptr[n], degInt[n], g2, lane);
    vs[(row << 6) + (lane ^ (row & 3))] = fmaf(sum, dinv[n], b2v);
  }
  __syncthreads();
  const int ng = lane >> 4, cg_ = lane & 15;
  // ---- layer 1: t1 = relu(v @ lw1 + lb1) ----
  float acc[4][4];
  #pragma unroll
  for (int j = 0; j < 4; ++j)
    #pragma unroll
    for (int c = 0; c < 4; ++c) acc[j][c] = lb1s[(cg_ << 2) + c];
  #pragma unroll 8
  for (int k = 0; k < 64; ++k) {
    float4 wv = *(const float4*)&w1s[(k << 6) + (cg_ << 2)];
    #pragma unroll
    for (int j = 0; j < 4; ++j) {
      int row = w * 16 + j * 4 + ng;
      float xv = vs[(row << 6) + (k ^ ng)];
      acc[j][0] = fmaf(xv, wv.x, acc[j][0]);
      acc[j][1] = fmaf(xv, wv.y, acc[j][1]);
      acc[j][2] = fmaf(xv, wv.z, acc[j][2]);
      acc[j][3] = fmaf(xv, wv.w, acc[j][3]);
    }
  }
  #pragma unroll
  for (int j = 0; j < 4; ++j) {
    int row = w * 16 + j * 4 + ng;
    #pragma unroll
    for (int c = 0; c < 4; ++c)
      t1s[(row << 6) + (((cg_ << 2) + c) ^ ng)] = fmaxf(acc[j][c], 0.f);
  }
  __syncthreads();
  // ---- layer 2: t2 = relu(t1 @ lw2 + lb2) ----
  float a2[4][2];
  #pragma unroll
  for (int j = 0; j < 4; ++j) {
    a2[j][0] = lb2s[(cg_ << 1)];
    a2[j][1] = lb2s[(cg_ << 1) + 1];
  }
  #pragma unroll 8
  for (int k = 0; k < 64; ++k) {
    float2 wv = *(const float2*)&w2s[(k << 5) + (cg_ << 1)];
    #pragma unroll
    for (int j = 0; j < 4; ++j) {
      int row = w * 16 + j * 4 + ng;
      float xv = t1s[(row << 6) + (k ^ ng)];
      a2[j][0] = fmaf(xv, wv.x, a2[j][0]);
      a2[j][1] = fmaf(xv, wv.y, a2[j][1]);
    }
  }
  // ---- layer 3: dot with w3, reduce across 16 cg lanes ----
  const float w3a = w3s[(cg_ << 1)], w3b = w3s[(cg_ << 1) + 1];
  #pragma unroll
  for (int j = 0; j < 4; ++j) {
    float p = fmaxf(a2[j][0], 0.f) * w3a + fmaxf(a2[j][1], 0.f) * w3b;
    p += __shfl_xor(p, 1, 64);
    p += __shfl_xor(p, 2, 64);
    p += __shfl_xor(p, 4, 64);
    p += __shfl_xor(p, 8, 64);
    int node = base + w * 16 + j * 4 + ng;
    if (cg_ == 0 && node < N) out[node] = p + lb3v;
  }
}

extern "C" void kernel_launch(void* const* d_in, const int* in_sizes, int n_in,
                              void* d_out, int out_size, void* d_ws, size_t ws_size,
                              hipStream_t stream) {
  const float* x   = (const float*)d_in[0];
  const int*   ei  = (const int*)d_in[1];
  const float* W1  = (const float*)d_in[2];
  const float* b1  = (const float*)d_in[3];
  const float* W2  = (const float*)d_in[4];
  const float* b2  = (const float*)d_in[5];
  const float* lw1 = (const float*)d_in[6];
  const float* lb1 = (const float*)d_in[7];
  const float* lw2 = (const float*)d_in[8];
  const float* lb2 = (const float*)d_in[9];
  const float* lw3 = (const float*)d_in[10];
  const float* lb3 = (const float*)d_in[11];
  float* out = (float*)d_out;

  int N = in_sizes[0] / IN_CH;
  int E = in_sizes[1] / 2;
  const int* src = ei;
  const int* dst = ei + E;
  int NBLKv = (E + TILE - 1) / TILE;              // 391
  int Pv    = (N + B2NODES - 1) >> B2SHIFT;       // 98
  int gb    = (N + 63) / 64;                      // 1563

  auto align256 = [](size_t v) { return (v + 255) & ~(size_t)255; };
  char* ws = (char*)d_ws;
  size_t nB = align256((size_t)N * 4);
  float* dinv   = (float*)ws;  ws += nB;
  int*   degInt = (int*)ws;    ws += nB;
  int*   rowptr = (int*)ws;    ws += nB;
  int*   H      = (int*)ws;    ws += align256((size_t)NBLKv * Pv * 4);
  int*   Orel   = (int*)ws;    ws += align256((size_t)NBLKv * Pv * 4);
  int*   colTot = (int*)ws;    ws += align256((size_t)Pv * 4);
  int*   csr    = (int*)ws;    ws += align256((size_t)E * 4);
  float* bufA   = (float*)ws;  ws += (size_t)N * HID * 4;  // g1
  float* bufB   = (float*)ws;                               // g2
  unsigned* pairBuf = (unsigned*)bufB;  // alias: dead before k_gg2 writes bufB

  // K1: cooperative build (CSR + dinv + gemm1), grid = 256 blocks (co-resident)
  void* args[] = { (void*)&src, (void*)&dst, (void*)&x, (void*)&W1, (void*)&H,
                   (void*)&Orel, (void*)&colTot, (void*)&pairBuf, (void*)&csr,
                   (void*)&rowptr, (void*)&degInt, (void*)&dinv, (void*)&bufA,
                   (void*)&N, (void*)&E, (void*)&NBLKv, (void*)&gb };
  hipLaunchCooperativeKernel((void*)k_build, dim3(256), dim3(256), args, 0, stream);

  // K2: gather(g1) + GEMM2 -> g2
  hipLaunchKernelGGL(k_gg2, dim3(gb), dim3(256), 0, stream,
                     rowptr, degInt, csr, bufA, dinv, b1, W2, bufB, N);
  // K3: gather(g2) + MLP -> out
  hipLaunchKernelGGL(k_gmlp, dim3(gb), dim3(256), 0, stream,
                     rowptr, degInt, csr, bufB, dinv, b2,
                     lw1, lb1, lw2, lb2, lw3, lb3, out, N);
}